// Round 8
// baseline (1324.260 us; speedup 1.0000x reference)
//
#include <hip/hip_runtime.h>
#include <cstdint>

#define Tn 200
#define En 512

// L1-bypass, L2-level 8B load (sc0): sees same-XCD stores without LLC trip.
__device__ __forceinline__ unsigned long long l2_load(const unsigned long long* p) {
  unsigned long long v;
  asm volatile("global_load_dwordx2 %0, %1, off sc0\n\ts_waitcnt vmcnt(0)"
               : "=v"(v) : "v"(p) : "memory");
  return v;
}

// ---- embed gather for batch row 63 only ----
__global__ __launch_bounds__(128) void embed_k(const int* __restrict__ ids,
                                               const float* __restrict__ tab,
                                               float* __restrict__ x0) {
  const int t = blockIdx.x;
  const int e = threadIdx.x;
  const long id = ids[63 * Tn + t];
  const float4* src = (const float4*)(tab + (size_t)id * En);
  ((float4*)(x0 + (size_t)t * En))[e] = src[e];
}

// out[t][g] = (relu?)( A[t][:512] . W[g][:512] + bp1[g] + bp2?[g] )
__global__ __launch_bounds__(256) void gemm_rows(const float* __restrict__ A,
                                                 const float* __restrict__ W,
                                                 const float* __restrict__ bp1,
                                                 const float* __restrict__ bp2,
                                                 float* __restrict__ out,
                                                 int G, int relu) {
  __shared__ float xl[8 * 512];
  const int gr = blockIdx.x * 256 + threadIdx.x;
  const int t0 = blockIdx.y * 8;
  for (int i = threadIdx.x; i < 8 * 512; i += 256) xl[i] = A[(size_t)t0 * 512 + i];
  __syncthreads();
  const float b = bp1[gr] + (bp2 ? bp2[gr] : 0.f);
  float acc[8];
#pragma unroll
  for (int tt = 0; tt < 8; tt++) acc[tt] = b;
  const float4* wr = (const float4*)(W + (size_t)gr * 512);
  for (int k4 = 0; k4 < 128; k4++) {
    const float4 w = wr[k4];
#pragma unroll
    for (int tt = 0; tt < 8; tt++) {
      const float4 xv = *(const float4*)&xl[tt * 512 + k4 * 4];
      acc[tt] = fmaf(w.x, xv.x, fmaf(w.y, xv.y, fmaf(w.z, xv.z, fmaf(w.w, xv.w, acc[tt]))));
    }
  }
#pragma unroll
  for (int tt = 0; tt < 8; tt++) {
    float v = acc[tt];
    if (relu) v = fmaxf(v, 0.f);
    out[(size_t)(t0 + tt) * G + gr] = v;
  }
}

// ---- bidirectional LSTM recurrence, XCD-pinned domains + L2-level polling ----
// Grid 64 blocks; workers: b&7==0 -> fwd domain (XCD0 by round-robin
// heuristic), b&7==1 -> bwd (XCD1); others exit. 8 WGs x 512 thr per domain,
// WG owns 32 h-elems = 128 gate rows. Thread (wave w, lane l):
// elem=w*4+(l>>4), gate=(l>>2)&3, kc=l&3; holds 64 whh floats as 16 named
// float4s. Exchange: 8B slot=(stamp<<32)|bits; producer agent-store (LLC
// visibility guaranteed); consumers poll at L2 level (sc0) with an
// agent-scope fallback probe every 16 iters -> correct even if the
// blockIdx->XCD heuristic is wrong, fast when it holds.
__global__ __launch_bounds__(512, 2) void rec_k(const float* __restrict__ xp,   // [T][2048] fwd|bwd
                                                float* __restrict__ hcat,       // [T][512]
                                                unsigned long long* __restrict__ ex, // [T][512]
                                                const float* __restrict__ whh,  // dir-major 2*1024*256
                                                unsigned stampbase) {
  __shared__ __align__(16) float hs[2][272];  // 4 chunks x 68 (stride pad)
  const int b = blockIdx.x;
  const int dir = b & 7;
  if (dir > 1) return;                  // 16 worker blocks, 48 exit
  const int wg = b >> 3;                // 0..7
  const int tid = threadIdx.x;
  const int lane = tid & 63, w = tid >> 6;
  const int elem = w * 4 + (lane >> 4);       // [0,32) within WG
  const int gate = (lane >> 2) & 3;
  const int kc = lane & 3;                    // 64-float k-chunk
  const int he = wg * 32 + elem;              // global h element [0,256)
  const int gr = gate * 256 + he;             // gate row (i|f|g|o blocks of 256)
  const float* whhD = whh + (size_t)dir * 262144;
  const float* xpD = xp + dir * 1024;

  float4 q0, q1, q2, q3, q4, q5, q6, q7, q8, q9, qa, qb, qc, qd, qe, qf;
  {
    const float4* p = (const float4*)(whhD + (size_t)gr * 256 + kc * 64);
    q0 = p[0]; q1 = p[1]; q2 = p[2]; q3 = p[3];
    q4 = p[4]; q5 = p[5]; q6 = p[6]; q7 = p[7];
    q8 = p[8]; q9 = p[9]; qa = p[10]; qb = p[11];
    qc = p[12]; qd = p[13]; qe = p[14]; qf = p[15];
  }
  for (int i = tid; i < 2 * 272; i += 512) ((float*)hs)[i] = 0.f;
  float c = 0.f;
  float xv = 0.f;
  if (kc == 0) xv = xpD[(size_t)(dir ? (Tn - 1) : 0) * 2048 + gr];
  const int isprod = ((lane & 15) == 0);
  const int base = lane & 48;
  const int iscons = (tid < 256) && ((tid >> 5) != wg);
  const int coff = ((tid & 255) >> 6) * 68 + (tid & 63);   // consumer LDS offset
  const int poff = (he >> 6) * 68 + (he & 63);             // producer LDS offset
  __syncthreads();  // init barrier

  for (int t = 0; t < Tn; ++t) {
    const int p = t & 1;
    // matvec on hs[p] = h(t-1): 16 b128 reads (4-addr broadcast, bank-clean)
    const float4* h4 = (const float4*)&hs[p][kc * 68];
    float a = 0.f;
#define FMA4(Q, H) a = fmaf(Q.x, H.x, a); a = fmaf(Q.y, H.y, a); \
                   a = fmaf(Q.z, H.z, a); a = fmaf(Q.w, H.w, a)
    { const float4 h0 = h4[0], h1 = h4[1], h2 = h4[2], h3 = h4[3];
      FMA4(q0, h0); FMA4(q1, h1); FMA4(q2, h2); FMA4(q3, h3); }
    { const float4 h0 = h4[4], h1 = h4[5], h2 = h4[6], h3 = h4[7];
      FMA4(q4, h0); FMA4(q5, h1); FMA4(q6, h2); FMA4(q7, h3); }
    { const float4 h0 = h4[8], h1 = h4[9], h2 = h4[10], h3 = h4[11];
      FMA4(q8, h0); FMA4(q9, h1); FMA4(qa, h2); FMA4(qb, h3); }
    { const float4 h0 = h4[12], h1 = h4[13], h2 = h4[14], h3 = h4[15];
      FMA4(qc, h0); FMA4(qd, h1); FMA4(qe, h2); FMA4(qf, h3); }
#undef FMA4
    a += __shfl_xor(a, 1);
    a += __shfl_xor(a, 2);
    if (kc == 0) a += xv;   // xproj (+both biases) folded in by gemm_rows
    // gather the 4 gate sums of each elem to its base lane (l&15==0)
    const float gi = __shfl(a, base + 0);
    const float gf = __shfl(a, base + 4);
    const float gg = __shfl(a, base + 8);
    const float go = __shfl(a, base + 12);
    if (isprod) {
      const float iv = 1.f / (1.f + __expf(-gi));
      const float fv = 1.f / (1.f + __expf(-gf));
      const float gv = 1.f - 2.f / (1.f + __expf(2.f * gg));
      const float ov = 1.f / (1.f + __expf(-go));
      c = fv * c + iv * gv;
      const float hv = ov * (1.f - 2.f / (1.f + __expf(2.f * c)));
      // agent-visible word first (critical path for remote WGs)
      __hip_atomic_store(&ex[(size_t)t * 512 + dir * 256 + he],
                         ((unsigned long long)(stampbase + t + 1) << 32) | __float_as_uint(hv),
                         __ATOMIC_RELAXED, __HIP_MEMORY_SCOPE_AGENT);
      hs[p ^ 1][poff] = hv;  // self-stage own element
      const int rowt = dir ? (Tn - 1 - t) : t;
      hcat[(size_t)rowt * 512 + dir * 256 + he] = hv;
    }
    if (t + 1 < Tn) {
      if (kc == 0)  // prefetch next step's xproj before the poll
        xv = xpD[(size_t)(dir ? (Tn - 2 - t) : (t + 1)) * 2048 + gr];
      if (iscons) {
        const unsigned long long* slot = &ex[(size_t)t * 512 + dir * 256 + tid];
        const unsigned tgt = stampbase + (unsigned)t + 1u;
        unsigned long long v;
        int gd = 0;
        for (;;) {
          v = l2_load(slot);                       // fast path: same-XCD L2
          if ((unsigned)(v >> 32) == tgt) break;
          ++gd;
          if ((gd & 15) == 0) {                    // fallback: LLC-level probe
            v = __hip_atomic_load(slot, __ATOMIC_RELAXED, __HIP_MEMORY_SCOPE_AGENT);
            if ((unsigned)(v >> 32) == tgt) break;
          }
          if (gd >= (1 << 20)) break;
        }
        hs[p ^ 1][coff] = __uint_as_float((unsigned)v);
      }
    }
    __syncthreads();  // h(t) staged; protects hs vs next step's writes
  }
}

// ---- final 1024->7 matmul + softmax per timestep ----
__global__ __launch_bounds__(64) void mlp2_k(const float* __restrict__ h1,
                                             const float* __restrict__ w2,
                                             const float* __restrict__ b2,
                                             float* __restrict__ out) {
  __shared__ float hrow[1024];
  __shared__ float lg[8];
  const int t = blockIdx.x, tid = threadIdx.x;
  for (int i = tid; i < 1024; i += 64) hrow[i] = h1[(size_t)t * 1024 + i];
  __syncthreads();
  const int o = tid >> 3, kc = tid & 7;
  float acc = 0.f;
  if (o < 7) {
    const float* wv = w2 + (size_t)o * 1024 + kc * 128;
    const float* h = &hrow[kc * 128];
    for (int jj = 0; jj < 128; jj++) acc = fmaf(wv[jj], h[jj], acc);
  }
#pragma unroll
  for (int off = 1; off < 8; off <<= 1) acc += __shfl_xor(acc, off);
  if (o < 7 && kc == 0) lg[o] = acc + b2[o];
  __syncthreads();
  if (tid == 0) {
    float mx = -1e30f;
#pragma unroll
    for (int i = 0; i < 7; i++) mx = fmaxf(mx, lg[i]);
    float e[7];
    float s = 0.f;
#pragma unroll
    for (int i = 0; i < 7; i++) { e[i] = __expf(lg[i] - mx); s += e[i]; }
    const float inv = 1.f / s;
#pragma unroll
    for (int i = 0; i < 7; i++) out[t * 7 + i] = e[i] * inv;
  }
}

extern "C" void kernel_launch(void* const* d_in, const int* in_sizes, int n_in,
                              void* d_out, int out_size, void* d_ws, size_t ws_size,
                              hipStream_t stream) {
  const int* ids = (const int*)d_in[0];
  const float* tab = (const float*)d_in[1];
  const float* wih = (const float*)d_in[2];   // (2,2,1024,512)
  const float* whh = (const float*)d_in[3];   // (2,2,1024,256)
  const float* bih = (const float*)d_in[4];   // (2,2,1024)
  const float* bhh = (const float*)d_in[5];
  const float* w1 = (const float*)d_in[6];    // (1024,512)
  const float* b1 = (const float*)d_in[7];
  const float* w2 = (const float*)d_in[8];    // (7,1024)
  const float* b2 = (const float*)d_in[9];
  float* out = (float*)d_out;                 // (200,7) f32
  float* ws = (float*)d_ws;

  float* x0 = ws;                     // 200*512
  float* xp = ws + 102400;            // 200*2048 (reused both layers)
  float* h0 = ws + 512000;            // 200*512
  float* h1 = ws + 614400;            // 200*512
  float* hm = ws + 716800;            // 200*1024
  unsigned long long* ex = (unsigned long long*)(ws + 921600);  // 200*512 8B slots

  // clear stamps from previous replay (slots are write-once within a launch)
  hipMemsetAsync(ex, 0, (size_t)Tn * 512 * 8, stream);
  embed_k<<<Tn, 128, 0, stream>>>(ids, tab, x0);
  // layer 0
  gemm_rows<<<dim3(8, 25), 256, 0, stream>>>(x0, wih, bih, bhh, xp, 2048, 0);
  rec_k<<<64, 512, 0, stream>>>(xp, h0, ex, whh, 0u);
  // layer 1 (shared ex buffer, disjoint stamp base)
  gemm_rows<<<dim3(8, 25), 256, 0, stream>>>(h0, wih + 1048576, bih + 2048, bhh + 2048, xp, 2048, 0);
  rec_k<<<64, 512, 0, stream>>>(xp, h1, ex, whh + 524288, 1000000u);
  // MLP
  gemm_rows<<<dim3(4, 25), 256, 0, stream>>>(h1, w1, b1, nullptr, hm, 1024, 1);
  mlp2_k<<<Tn, 64, 0, stream>>>(hm, w2, b2, out);
}

// Round 9
// 863.033 us; speedup vs baseline: 1.5344x; 1.5344x over previous
//
#include <hip/hip_runtime.h>
#include <cstdint>

#define Tn 200
#define En 512

// L1-bypass L2-level 8B load (sc0): sees same-XCD write-through stores.
__device__ __forceinline__ unsigned long long l2_load(const unsigned long long* p) {
  unsigned long long v;
  asm volatile("global_load_dwordx2 %0, %1, off sc0\n\ts_waitcnt vmcnt(0)"
               : "=v"(v) : "v"(p) : "memory");
  return v;
}

// ---- embed gather for batch row 63 only ----
__global__ __launch_bounds__(128) void embed_k(const int* __restrict__ ids,
                                               const float* __restrict__ tab,
                                               float* __restrict__ x0) {
  const int t = blockIdx.x;
  const int e = threadIdx.x;
  const long id = ids[63 * Tn + t];
  const float4* src = (const float4*)(tab + (size_t)id * En);
  ((float4*)(x0 + (size_t)t * En))[e] = src[e];
}

// out[t][g] = (relu?)( A[t][:512] . W[g][:512] + bp1[g] + bp2?[g] )
__global__ __launch_bounds__(256) void gemm_rows(const float* __restrict__ A,
                                                 const float* __restrict__ W,
                                                 const float* __restrict__ bp1,
                                                 const float* __restrict__ bp2,
                                                 float* __restrict__ out,
                                                 int G, int relu) {
  __shared__ float xl[8 * 512];
  const int gr = blockIdx.x * 256 + threadIdx.x;
  const int t0 = blockIdx.y * 8;
  for (int i = threadIdx.x; i < 8 * 512; i += 256) xl[i] = A[(size_t)t0 * 512 + i];
  __syncthreads();
  const float b = bp1[gr] + (bp2 ? bp2[gr] : 0.f);
  float acc[8];
#pragma unroll
  for (int tt = 0; tt < 8; tt++) acc[tt] = b;
  const float4* wr = (const float4*)(W + (size_t)gr * 512);
  for (int k4 = 0; k4 < 128; k4++) {
    const float4 w = wr[k4];
#pragma unroll
    for (int tt = 0; tt < 8; tt++) {
      const float4 xv = *(const float4*)&xl[tt * 512 + k4 * 4];
      acc[tt] = fmaf(w.x, xv.x, fmaf(w.y, xv.y, fmaf(w.z, xv.z, fmaf(w.w, xv.w, acc[tt]))));
    }
  }
#pragma unroll
  for (int tt = 0; tt < 8; tt++) {
    float v = acc[tt];
    if (relu) v = fmaxf(v, 0.f);
    out[(size_t)(t0 + tt) * G + gr] = v;
  }
}

// ---- bidirectional LSTM recurrence: XCD-local L2 exchange ----
// Grid 128; workers b%8==0 (fwd, XCD0 by round-robin heuristic) and b%8==1
// (bwd, XCD1); 16 WGs x 512 thr per domain (R3's proven geometry), 84KB LDS
// pad -> 1 WG/CU. Producer h-word: WORKGROUP-scope store (write-through
// L1 -> XCD L2; fast slots stay valid-in-place in L2, unlike agent/sc1
// stores which write-around and leave consumers spinning on stale lines =
// R8's failure) + AGENT-scope store to a separate slow buffer (LLC) for
// cross-XCD correctness fallback. Consumers: sc0 poll fast slot, agent
// probe of slow slot every 8 misses. Single barrier/step, double-buffered
// hs, producers self-stage own elems.
__global__ __launch_bounds__(512, 2) void rec_k(const float* __restrict__ xp,   // [T][2048] fwd|bwd
                                                float* __restrict__ hcat,       // [T][512]
                                                unsigned long long* __restrict__ exf, // fast [T][512]
                                                unsigned long long* __restrict__ exs, // slow [T][512]
                                                const float* __restrict__ whh,  // dir-major 2*1024*256
                                                unsigned stampbase) {
  __shared__ __align__(16) float hs[2][288];  // stride-36 chunks, double buffer
  __shared__ float pad[21000];                // forces 1 WG/CU (>80KB total)
  const int b = blockIdx.x;
  const int dir = b & 7;
  if (dir > 1) return;                 // 32 worker blocks, 96 exit
  const int wg = b >> 3;               // 0..15
  const int tid = threadIdx.x;
  const int lane = tid & 63;
  const int row = tid >> 3, kc = tid & 7;
  const int elem = row >> 2, gate = row & 3;
  const int he = wg * 16 + elem;        // global h element [0,256)
  const int gr = gate * 256 + he;       // gate row (i|f|g|o blocks of 256)
  const float* whhD = whh + (size_t)dir * 262144;
  const float* xpD = xp + dir * 1024;

  if (stampbase == 0xDEADBEEFu) {  // never true at runtime; keeps pad live
    pad[tid] = xp[tid];
    hcat[tid] = pad[tid ^ 1];
  }

  float4 q0, q1, q2, q3, q4, q5, q6, q7;
  {
    const float4* p = (const float4*)(whhD + (size_t)gr * 256 + kc * 32);
    q0 = p[0]; q1 = p[1]; q2 = p[2]; q3 = p[3];
    q4 = p[4]; q5 = p[5]; q6 = p[6]; q7 = p[7];
  }
  for (int i = tid; i < 2 * 288; i += 512) ((float*)hs)[i] = 0.f;
  float c = 0.f;
  float xv = 0.f;
  if (kc == 0) xv = xpD[(size_t)(dir ? (Tn - 1) : 0) * 2048 + gr];
  const int isprod = ((lane & 31) == 0);
  const int base = lane & 32;
  const int iscons = (tid < 256) && ((tid >> 4) != wg);
  const int coff = ((tid & 255) >> 5) * 36 + (tid & 31);   // consumer LDS offset
  const int poff = (he >> 5) * 36 + (he & 31);             // producer LDS offset
  __syncthreads();  // init barrier

  for (int t = 0; t < Tn; ++t) {
    const int p = t & 1;
    // matvec on hs[p] = h(t-1)
    const float4* h4 = (const float4*)&hs[p][kc * 36];
    const float4 h0 = h4[0], h1 = h4[1], h2 = h4[2], h3 = h4[3];
    const float4 h5 = h4[4], h6 = h4[5], h7 = h4[6], h8 = h4[7];
    float a = 0.f;
    a = fmaf(q0.x, h0.x, a); a = fmaf(q0.y, h0.y, a); a = fmaf(q0.z, h0.z, a); a = fmaf(q0.w, h0.w, a);
    a = fmaf(q1.x, h1.x, a); a = fmaf(q1.y, h1.y, a); a = fmaf(q1.z, h1.z, a); a = fmaf(q1.w, h1.w, a);
    a = fmaf(q2.x, h2.x, a); a = fmaf(q2.y, h2.y, a); a = fmaf(q2.z, h2.z, a); a = fmaf(q2.w, h2.w, a);
    a = fmaf(q3.x, h3.x, a); a = fmaf(q3.y, h3.y, a); a = fmaf(q3.z, h3.z, a); a = fmaf(q3.w, h3.w, a);
    a = fmaf(q4.x, h5.x, a); a = fmaf(q4.y, h5.y, a); a = fmaf(q4.z, h5.z, a); a = fmaf(q4.w, h5.w, a);
    a = fmaf(q5.x, h6.x, a); a = fmaf(q5.y, h6.y, a); a = fmaf(q5.z, h6.z, a); a = fmaf(q5.w, h6.w, a);
    a = fmaf(q6.x, h7.x, a); a = fmaf(q6.y, h7.y, a); a = fmaf(q6.z, h7.z, a); a = fmaf(q6.w, h7.w, a);
    a = fmaf(q7.x, h8.x, a); a = fmaf(q7.y, h8.y, a); a = fmaf(q7.z, h8.z, a); a = fmaf(q7.w, h8.w, a);
    a += __shfl_xor(a, 1);
    a += __shfl_xor(a, 2);
    a += __shfl_xor(a, 4);
    // kc==0 roots: add xproj and apply this gate's activation in parallel
    if (kc == 0) {
      a += xv;
      const float sg = 1.f / (1.f + __expf(-a));
      const float th = 1.f - 2.f / (1.f + __expf(2.f * a));
      a = (gate == 2) ? th : sg;
    }
    // gather the 4 ACTIVATED gates of this wave's two elements to lanes 0/32
    const float gi = __shfl(a, base + 0);
    const float gf = __shfl(a, base + 8);
    const float gg = __shfl(a, base + 16);
    const float go = __shfl(a, base + 24);
    if (isprod) {
      c = gf * c + gi * gg;
      const float hv = go * (1.f - 2.f / (1.f + __expf(2.f * c)));
      const unsigned long long word =
          ((unsigned long long)(stampbase + t + 1) << 32) | __float_as_uint(hv);
      // fast: write-through to XCD L2 (stays valid in place)
      __hip_atomic_store(&exf[(size_t)t * 512 + dir * 256 + he], word,
                         __ATOMIC_RELAXED, __HIP_MEMORY_SCOPE_WORKGROUP);
      // slow: LLC-visible fallback for cross-XCD consumers
      __hip_atomic_store(&exs[(size_t)t * 512 + dir * 256 + he], word,
                         __ATOMIC_RELAXED, __HIP_MEMORY_SCOPE_AGENT);
      hs[p ^ 1][poff] = hv;  // self-stage own element
      const int rowt = dir ? (Tn - 1 - t) : t;
      hcat[(size_t)rowt * 512 + dir * 256 + he] = hv;
    }
    if (t + 1 < Tn) {
      if (kc == 0)  // prefetch next step's xproj before the poll
        xv = xpD[(size_t)(dir ? (Tn - 2 - t) : (t + 1)) * 2048 + gr];
      if (iscons) {
        const unsigned long long* fslot = &exf[(size_t)t * 512 + dir * 256 + tid];
        const unsigned long long* sslot = &exs[(size_t)t * 512 + dir * 256 + tid];
        const unsigned tgt = stampbase + (unsigned)t + 1u;
        unsigned long long v;
        int gd = 0;
        for (;;) {
          v = l2_load(fslot);                     // fast: same-XCD L2
          if ((unsigned)(v >> 32) == tgt) break;
          ++gd;
          if ((gd & 7) == 0) {                    // fallback: LLC probe
            v = __hip_atomic_load(sslot, __ATOMIC_RELAXED, __HIP_MEMORY_SCOPE_AGENT);
            if ((unsigned)(v >> 32) == tgt) break;
          }
          if (gd >= (1 << 20)) break;
        }
        hs[p ^ 1][coff] = __uint_as_float((unsigned)v);
      }
    }
    __syncthreads();  // h(t) staged; protects hs[p] reads vs next overwrite
  }
}

// ---- final 1024->7 matmul + softmax per timestep ----
__global__ __launch_bounds__(64) void mlp2_k(const float* __restrict__ h1,
                                             const float* __restrict__ w2,
                                             const float* __restrict__ b2,
                                             float* __restrict__ out) {
  __shared__ float hrow[1024];
  __shared__ float lg[8];
  const int t = blockIdx.x, tid = threadIdx.x;
  for (int i = tid; i < 1024; i += 64) hrow[i] = h1[(size_t)t * 1024 + i];
  __syncthreads();
  const int o = tid >> 3, kc = tid & 7;
  float acc = 0.f;
  if (o < 7) {
    const float* wv = w2 + (size_t)o * 1024 + kc * 128;
    const float* h = &hrow[kc * 128];
    for (int jj = 0; jj < 128; jj++) acc = fmaf(wv[jj], h[jj], acc);
  }
#pragma unroll
  for (int off = 1; off < 8; off <<= 1) acc += __shfl_xor(acc, off);
  if (o < 7 && kc == 0) lg[o] = acc + b2[o];
  __syncthreads();
  if (tid == 0) {
    float mx = -1e30f;
#pragma unroll
    for (int i = 0; i < 7; i++) mx = fmaxf(mx, lg[i]);
    float e[7];
    float s = 0.f;
#pragma unroll
    for (int i = 0; i < 7; i++) { e[i] = __expf(lg[i] - mx); s += e[i]; }
    const float inv = 1.f / s;
#pragma unroll
    for (int i = 0; i < 7; i++) out[t * 7 + i] = e[i] * inv;
  }
}

extern "C" void kernel_launch(void* const* d_in, const int* in_sizes, int n_in,
                              void* d_out, int out_size, void* d_ws, size_t ws_size,
                              hipStream_t stream) {
  const int* ids = (const int*)d_in[0];
  const float* tab = (const float*)d_in[1];
  const float* wih = (const float*)d_in[2];   // (2,2,1024,512)
  const float* whh = (const float*)d_in[3];   // (2,2,1024,256)
  const float* bih = (const float*)d_in[4];   // (2,2,1024)
  const float* bhh = (const float*)d_in[5];
  const float* w1 = (const float*)d_in[6];    // (1024,512)
  const float* b1 = (const float*)d_in[7];
  const float* w2 = (const float*)d_in[8];    // (7,1024)
  const float* b2 = (const float*)d_in[9];
  float* out = (float*)d_out;                 // (200,7) f32
  float* ws = (float*)d_ws;

  float* x0 = ws;                     // 200*512
  float* xp = ws + 102400;            // 200*2048 (reused both layers)
  float* h0 = ws + 512000;            // 200*512
  float* h1 = ws + 614400;            // 200*512
  float* hm = ws + 716800;            // 200*1024
  unsigned long long* exf = (unsigned long long*)(ws + 921600);   // fast slots
  unsigned long long* exs = exf + (size_t)Tn * 512;               // slow slots

  // clear stamps from previous replay (slots are write-once within a launch)
  hipMemsetAsync(exf, 0, (size_t)Tn * 512 * 8 * 2, stream);
  embed_k<<<Tn, 128, 0, stream>>>(ids, tab, x0);
  // layer 0
  gemm_rows<<<dim3(8, 25), 256, 0, stream>>>(x0, wih, bih, bhh, xp, 2048, 0);
  rec_k<<<128, 512, 0, stream>>>(xp, h0, exf, exs, whh, 0u);
  // layer 1 (shared ex buffers, disjoint stamp base)
  gemm_rows<<<dim3(8, 25), 256, 0, stream>>>(h0, wih + 1048576, bih + 2048, bhh + 2048, xp, 2048, 0);
  rec_k<<<128, 512, 0, stream>>>(xp, h1, exf, exs, whh + 524288, 1000000u);
  // MLP
  gemm_rows<<<dim3(4, 25), 256, 0, stream>>>(h1, w1, b1, nullptr, hm, 1024, 1);
  mlp2_k<<<Tn, 64, 0, stream>>>(hm, w2, b2, out);
}

// Round 10
// 724.701 us; speedup vs baseline: 1.8273x; 1.1909x over previous
//
#include <hip/hip_runtime.h>
#include <cstdint>

#define Tn 200
#define En 512

// L1-bypass L2-level 8B load (sc0): sees same-XCD write-through stores.
__device__ __forceinline__ unsigned long long l2_load(const unsigned long long* p) {
  unsigned long long v;
  asm volatile("global_load_dwordx2 %0, %1, off sc0\n\ts_waitcnt vmcnt(0)"
               : "=v"(v) : "v"(p) : "memory");
  return v;
}

// ---- embed gather for batch row 63 only ----
__global__ __launch_bounds__(128) void embed_k(const int* __restrict__ ids,
                                               const float* __restrict__ tab,
                                               float* __restrict__ x0) {
  const int t = blockIdx.x;
  const int e = threadIdx.x;
  const long id = ids[63 * Tn + t];
  const float4* src = (const float4*)(tab + (size_t)id * En);
  ((float4*)(x0 + (size_t)t * En))[e] = src[e];
}

// out[t][g] = (relu?)( A[t][:512] . W[g][:512] + bp1[g] + bp2?[g] )
__global__ __launch_bounds__(256) void gemm_rows(const float* __restrict__ A,
                                                 const float* __restrict__ W,
                                                 const float* __restrict__ bp1,
                                                 const float* __restrict__ bp2,
                                                 float* __restrict__ out,
                                                 int G, int relu) {
  __shared__ float xl[8 * 512];
  const int gr = blockIdx.x * 256 + threadIdx.x;
  const int t0 = blockIdx.y * 8;
  for (int i = threadIdx.x; i < 8 * 512; i += 256) xl[i] = A[(size_t)t0 * 512 + i];
  __syncthreads();
  const float b = bp1[gr] + (bp2 ? bp2[gr] : 0.f);
  float acc[8];
#pragma unroll
  for (int tt = 0; tt < 8; tt++) acc[tt] = b;
  const float4* wr = (const float4*)(W + (size_t)gr * 512);
  for (int k4 = 0; k4 < 128; k4++) {
    const float4 w = wr[k4];
#pragma unroll
    for (int tt = 0; tt < 8; tt++) {
      const float4 xv = *(const float4*)&xl[tt * 512 + k4 * 4];
      acc[tt] = fmaf(w.x, xv.x, fmaf(w.y, xv.y, fmaf(w.z, xv.z, fmaf(w.w, xv.w, acc[tt]))));
    }
  }
#pragma unroll
  for (int tt = 0; tt < 8; tt++) {
    float v = acc[tt];
    if (relu) v = fmaxf(v, 0.f);
    out[(size_t)(t0 + tt) * G + gr] = v;
  }
}

// ---- bidirectional LSTM recurrence: XCD-local L2 exchange, naked barrier ----
// Grid 128; workers b%8==0 (fwd->XCD0 heuristic) / b%8==1 (bwd->XCD1);
// 16 WGs x 512 thr/domain, LDS pad -> 1 WG/CU. Key changes vs R9 (all aimed
// at removing store-ack serialization from the per-step critical path):
//  1) naked `s_waitcnt lgkmcnt(0); s_barrier` instead of __syncthreads():
//     __syncthreads drains vmcnt(0), convoying every step on producer
//     store acks (incl ~400ns LLC ack) + xv prefetch returns.
//  2) producers (tid%32==0) never poll; 240 pollers are non-producers, so
//     no poller waits its own store acks inside the poll's vmcnt(0).
//  3) xv prefetch issued AFTER poll success (never before a probe).
//  4) hcat stores moved to an epilogue copy from exf (own-WG values).
// Exchange unchanged: 8B word=(stamp<<32)|bits; producer stores it
// workgroup-scope to exf (write-through -> XCD L2, line updated in place)
// and agent-scope to exs (LLC) for cross-XCD fallback; pollers sc0-poll
// exf with an agent probe of exs every 4 misses (correct either way).
__global__ __launch_bounds__(512, 2) void rec_k(const float* __restrict__ xp,   // [T][2048] fwd|bwd
                                                float* __restrict__ hcat,       // [T][512]
                                                unsigned long long* __restrict__ exf, // fast [T][512]
                                                unsigned long long* __restrict__ exs, // slow [T][512]
                                                const float* __restrict__ whh,  // dir-major 2*1024*256
                                                unsigned stampbase) {
  __shared__ __align__(16) float hs[2][288];  // stride-36 chunks, double buffer
  __shared__ float pad[21000];                // forces 1 WG/CU (>80KB total)
  const int b = blockIdx.x;
  const int dir = b & 7;
  if (dir > 1) return;                 // 32 worker blocks, 96 exit
  const int wg = b >> 3;               // 0..15
  const int tid = threadIdx.x;
  const int lane = tid & 63;
  const int row = tid >> 3, kc = tid & 7;
  const int elem = row >> 2, gate = row & 3;
  const int he = wg * 16 + elem;        // global h element [0,256)
  const int gr = gate * 256 + he;       // gate row (i|f|g|o blocks of 256)
  const float* whhD = whh + (size_t)dir * 262144;
  const float* xpD = xp + dir * 1024;

  if (stampbase == 0xDEADBEEFu) {  // never true at runtime; keeps pad live
    pad[tid] = xp[tid];
    hcat[tid] = pad[tid ^ 1];
  }

  float4 q0, q1, q2, q3, q4, q5, q6, q7;
  {
    const float4* p = (const float4*)(whhD + (size_t)gr * 256 + kc * 32);
    q0 = p[0]; q1 = p[1]; q2 = p[2]; q3 = p[3];
    q4 = p[4]; q5 = p[5]; q6 = p[6]; q7 = p[7];
  }
  for (int i = tid; i < 2 * 288; i += 512) ((float*)hs)[i] = 0.f;
  float c = 0.f;
  float xv = 0.f;
  if (kc == 0) xv = xpD[(size_t)(dir ? (Tn - 1) : 0) * 2048 + gr];
  const int isprod = ((lane & 31) == 0);   // tid%32==0: 16 producers
  const int base = lane & 32;
  // poller mapping: rank among non-producers; first 240 ranks poll the 240
  // remote slots (own-WG 16 slots are self-staged by producers).
  const int pr = tid - 1 - (tid >> 5);
  const int ispoll = (!isprod) && (pr < 240);
  const int slot = ispoll ? (pr + (pr >= wg * 16 ? 16 : 0)) : 0;
  const int coff = (slot >> 5) * 36 + (slot & 31);
  const int poff = (he >> 5) * 36 + (he & 31);
  __syncthreads();  // init barrier (full drain, once)

  for (int t = 0; t < Tn; ++t) {
    const int p = t & 1;
    // matvec on hs[p] = h(t-1)
    const float4* h4 = (const float4*)&hs[p][kc * 36];
    const float4 h0 = h4[0], h1 = h4[1], h2 = h4[2], h3 = h4[3];
    const float4 h5 = h4[4], h6 = h4[5], h7 = h4[6], h8 = h4[7];
    float a = 0.f;
    a = fmaf(q0.x, h0.x, a); a = fmaf(q0.y, h0.y, a); a = fmaf(q0.z, h0.z, a); a = fmaf(q0.w, h0.w, a);
    a = fmaf(q1.x, h1.x, a); a = fmaf(q1.y, h1.y, a); a = fmaf(q1.z, h1.z, a); a = fmaf(q1.w, h1.w, a);
    a = fmaf(q2.x, h2.x, a); a = fmaf(q2.y, h2.y, a); a = fmaf(q2.z, h2.z, a); a = fmaf(q2.w, h2.w, a);
    a = fmaf(q3.x, h3.x, a); a = fmaf(q3.y, h3.y, a); a = fmaf(q3.z, h3.z, a); a = fmaf(q3.w, h3.w, a);
    a = fmaf(q4.x, h5.x, a); a = fmaf(q4.y, h5.y, a); a = fmaf(q4.z, h5.z, a); a = fmaf(q4.w, h5.w, a);
    a = fmaf(q5.x, h6.x, a); a = fmaf(q5.y, h6.y, a); a = fmaf(q5.z, h6.z, a); a = fmaf(q5.w, h6.w, a);
    a = fmaf(q6.x, h7.x, a); a = fmaf(q6.y, h7.y, a); a = fmaf(q6.z, h7.z, a); a = fmaf(q6.w, h7.w, a);
    a = fmaf(q7.x, h8.x, a); a = fmaf(q7.y, h8.y, a); a = fmaf(q7.z, h8.z, a); a = fmaf(q7.w, h8.w, a);
    a += __shfl_xor(a, 1);
    a += __shfl_xor(a, 2);
    a += __shfl_xor(a, 4);
    // kc==0 roots: add xproj and apply this gate's activation in parallel
    if (kc == 0) {
      a += xv;
      const float sg = 1.f / (1.f + __expf(-a));
      const float th = 1.f - 2.f / (1.f + __expf(2.f * a));
      a = (gate == 2) ? th : sg;
    }
    // gather the 4 ACTIVATED gates of this wave's two elements to lanes 0/32
    const float gi = __shfl(a, base + 0);
    const float gf = __shfl(a, base + 8);
    const float gg = __shfl(a, base + 16);
    const float go = __shfl(a, base + 24);
    if (isprod) {
      c = gf * c + gi * gg;
      const float hv = go * (1.f - 2.f / (1.f + __expf(2.f * c)));
      const unsigned long long word =
          ((unsigned long long)(stampbase + t + 1) << 32) | __float_as_uint(hv);
      // both stores fire-and-forget: acks never waited (naked barrier)
      __hip_atomic_store(&exs[(size_t)t * 512 + dir * 256 + he], word,
                         __ATOMIC_RELAXED, __HIP_MEMORY_SCOPE_AGENT);
      __hip_atomic_store(&exf[(size_t)t * 512 + dir * 256 + he], word,
                         __ATOMIC_RELAXED, __HIP_MEMORY_SCOPE_WORKGROUP);
      hs[p ^ 1][poff] = hv;  // self-stage own element
    } else if (ispoll && t + 1 < Tn) {
      const unsigned long long* fslot = &exf[(size_t)t * 512 + dir * 256 + slot];
      const unsigned long long* sslot = &exs[(size_t)t * 512 + dir * 256 + slot];
      const unsigned tgt = stampbase + (unsigned)t + 1u;
      unsigned long long v;
      int gd = 0;
      for (;;) {
        v = l2_load(fslot);                     // fast: same-XCD L2
        if ((unsigned)(v >> 32) == tgt) break;
        ++gd;
        if ((gd & 3) == 0) {                    // fallback: LLC probe
          v = __hip_atomic_load(sslot, __ATOMIC_RELAXED, __HIP_MEMORY_SCOPE_AGENT);
          if ((unsigned)(v >> 32) == tgt) break;
        }
        if (gd >= (1 << 20)) break;
      }
      hs[p ^ 1][coff] = __uint_as_float((unsigned)v);
    }
    if (kc == 0 && t + 1 < Tn)  // xv prefetch AFTER poll; floats across barrier
      xv = xpD[(size_t)(dir ? (Tn - 2 - t) : (t + 1)) * 2048 + gr];
    // naked barrier: LDS ordering only, no vmcnt drain
    asm volatile("s_waitcnt lgkmcnt(0)\n\ts_barrier" ::: "memory");
  }

  // epilogue: write hcat from exf (own-WG words; own-CU L1/L2 visibility)
  __syncthreads();
  for (int i = tid; i < 16 * Tn; i += 512) {
    const int t = i >> 4, e2 = i & 15;
    const int h2 = wg * 16 + e2;
    const unsigned long long wv2 = exf[(size_t)t * 512 + dir * 256 + h2];
    const int rowt = dir ? (Tn - 1 - t) : t;
    hcat[(size_t)rowt * 512 + dir * 256 + h2] = __uint_as_float((unsigned)wv2);
  }
}

// ---- final 1024->7 matmul + softmax per timestep ----
__global__ __launch_bounds__(64) void mlp2_k(const float* __restrict__ h1,
                                             const float* __restrict__ w2,
                                             const float* __restrict__ b2,
                                             float* __restrict__ out) {
  __shared__ float hrow[1024];
  __shared__ float lg[8];
  const int t = blockIdx.x, tid = threadIdx.x;
  for (int i = tid; i < 1024; i += 64) hrow[i] = h1[(size_t)t * 1024 + i];
  __syncthreads();
  const int o = tid >> 3, kc = tid & 7;
  float acc = 0.f;
  if (o < 7) {
    const float* wv = w2 + (size_t)o * 1024 + kc * 128;
    const float* h = &hrow[kc * 128];
    for (int jj = 0; jj < 128; jj++) acc = fmaf(wv[jj], h[jj], acc);
  }
#pragma unroll
  for (int off = 1; off < 8; off <<= 1) acc += __shfl_xor(acc, off);
  if (o < 7 && kc == 0) lg[o] = acc + b2[o];
  __syncthreads();
  if (tid == 0) {
    float mx = -1e30f;
#pragma unroll
    for (int i = 0; i < 7; i++) mx = fmaxf(mx, lg[i]);
    float e[7];
    float s = 0.f;
#pragma unroll
    for (int i = 0; i < 7; i++) { e[i] = __expf(lg[i] - mx); s += e[i]; }
    const float inv = 1.f / s;
#pragma unroll
    for (int i = 0; i < 7; i++) out[t * 7 + i] = e[i] * inv;
  }
}

extern "C" void kernel_launch(void* const* d_in, const int* in_sizes, int n_in,
                              void* d_out, int out_size, void* d_ws, size_t ws_size,
                              hipStream_t stream) {
  const int* ids = (const int*)d_in[0];
  const float* tab = (const float*)d_in[1];
  const float* wih = (const float*)d_in[2];   // (2,2,1024,512)
  const float* whh = (const float*)d_in[3];   // (2,2,1024,256)
  const float* bih = (const float*)d_in[4];   // (2,2,1024)
  const float* bhh = (const float*)d_in[5];
  const float* w1 = (const float*)d_in[6];    // (1024,512)
  const float* b1 = (const float*)d_in[7];
  const float* w2 = (const float*)d_in[8];    // (7,1024)
  const float* b2 = (const float*)d_in[9];
  float* out = (float*)d_out;                 // (200,7) f32
  float* ws = (float*)d_ws;

  float* x0 = ws;                     // 200*512
  float* xp = ws + 102400;            // 200*2048 (reused both layers)
  float* h0 = ws + 512000;            // 200*512
  float* h1 = ws + 614400;            // 200*512
  float* hm = ws + 716800;            // 200*1024
  unsigned long long* exf = (unsigned long long*)(ws + 921600);   // fast slots
  unsigned long long* exs = exf + (size_t)Tn * 512;               // slow slots

  // clear stamps from previous replay (slots are write-once within a launch)
  hipMemsetAsync(exf, 0, (size_t)Tn * 512 * 8 * 2, stream);
  embed_k<<<Tn, 128, 0, stream>>>(ids, tab, x0);
  // layer 0
  gemm_rows<<<dim3(8, 25), 256, 0, stream>>>(x0, wih, bih, bhh, xp, 2048, 0);
  rec_k<<<128, 512, 0, stream>>>(xp, h0, exf, exs, whh, 0u);
  // layer 1 (shared ex buffers, disjoint stamp base)
  gemm_rows<<<dim3(8, 25), 256, 0, stream>>>(h0, wih + 1048576, bih + 2048, bhh + 2048, xp, 2048, 0);
  rec_k<<<128, 512, 0, stream>>>(xp, h1, exf, exs, whh + 524288, 1000000u);
  // MLP
  gemm_rows<<<dim3(4, 25), 256, 0, stream>>>(h1, w1, b1, nullptr, hm, 1024, 1);
  mlp2_k<<<Tn, 64, 0, stream>>>(hm, w2, b2, out);
}